// Round 8
// baseline (2134.200 us; speedup 1.0000x reference)
//
#include <hip/hip_runtime.h>
#include <hip/hip_bf16.h>

#define NATTRS 200
#define NOBJS  500
#define NNODE  700
#define IN_F   512
#define HID    2048
#define NODE_D 512
#define IMG_D  512
#define EMB    800
#define BB     256
#define P_H1   1000
#define NPAIR  100000

typedef __attribute__((ext_vector_type(8))) short short8v;
typedef __attribute__((ext_vector_type(4))) float f32x4;

// ---------------- async global->LDS (16B) ----------------
typedef const __attribute__((address_space(1))) unsigned int* gas_ptr;
typedef __attribute__((address_space(3))) unsigned int* las_ptr;
__device__ __forceinline__ void async_copy16(void* lds, const void* g) {
  __builtin_amdgcn_global_load_lds((gas_ptr)g, (las_ptr)lds, 16, 0, 0);
}

__device__ __forceinline__ ushort f2bf(float x) {
  __hip_bfloat16 b = __float2bfloat16(x);
  return *reinterpret_cast<ushort*>(&b);
}
__device__ __forceinline__ float bf2f(ushort u) {
  __hip_bfloat16 b;
  *reinterpret_cast<ushort*>(&b) = u;
  return __bfloat162float(b);
}

// ---------------- CSR build ----------------
__global__ void k_count(const int* __restrict__ ei, int* __restrict__ cnt, int E) {
  int e = blockIdx.x * 256 + threadIdx.x;
  if (e < E) atomicAdd(&cnt[ei[E + e]], 1);
}

__global__ __launch_bounds__(1024) void k_scan(const int* __restrict__ cnt,
                                               int* __restrict__ row_start,
                                               int* __restrict__ pos) {
  __shared__ int s[1024];
  int t = threadIdx.x;
  int my = (t < NNODE) ? cnt[t] : 0;
  s[t] = my;
  __syncthreads();
  for (int off = 1; off < 1024; off <<= 1) {
    int add = (t >= off) ? s[t - off] : 0;
    __syncthreads();
    s[t] += add;
    __syncthreads();
  }
  int excl = s[t] - my;
  if (t < NNODE) { row_start[t] = excl; pos[t] = excl; }
  if (t == 0) row_start[NNODE] = s[1023];
}

__global__ void k_fill(const int* __restrict__ ei, int* __restrict__ pos,
                       int* __restrict__ srcs, int E) {
  int e = blockIdx.x * 256 + threadIdx.x;
  if (e < E) {
    int d = ei[E + e];
    int idx = atomicAdd(&pos[d], 1);
    srcs[idx] = ei[e];
  }
}

__global__ __launch_bounds__(256) void agg_mean(const float* __restrict__ X,
                                                const int* __restrict__ srcs,
                                                const int* __restrict__ row_start,
                                                float* __restrict__ outp, int D) {
  int node = blockIdx.x;
  int d = blockIdx.y * 256 + threadIdx.x;
  int e0 = row_start[node], e1 = row_start[node + 1];
  float s = 0.f;
  for (int e = e0; e < e1; ++e) s += X[srcs[e] * D + d];
  float c = (float)(e1 - e0);
  outp[node * D + d] = s / fmaxf(c, 1.f);
}

// ---------------- split: X f32 [Mvalid][K] -> hi/lo bf16 [Mpad][Kpad], zero pad ------------
__global__ __launch_bounds__(256) void split_f32(const float* __restrict__ X,
                                                 ushort* __restrict__ Xh,
                                                 ushort* __restrict__ Xl,
                                                 int Mvalid, int K, int Kpad, long total) {
  for (long idx = blockIdx.x * 256L + threadIdx.x; idx < total; idx += gridDim.x * 256L) {
    int m = (int)(idx / Kpad);
    int k = (int)(idx - (long)m * Kpad);
    float v = (m < Mvalid && k < K) ? X[(size_t)m * K + k] : 0.f;
    ushort h = f2bf(v);
    Xh[idx] = h;
    Xl[idx] = f2bf(v - bf2f(h));
  }
}

// ---------------- batched weight transpose+split: W [K][N] -> [Npad][Kpad] hi/lo ------------
struct WDesc { const float* W; ushort* Wh; ushort* Wl; int K, N, Kpad, nbx, blk0; };
struct WBatch { WDesc d[10]; };

__global__ __launch_bounds__(256) void prep_wT_batch(WBatch B) {
  __shared__ float tile[32][33];
  int bx = blockIdx.x;
  int di = 0;
  #pragma unroll
  for (int j = 1; j < 10; ++j) if (bx >= B.d[j].blk0) di = j;
  const WDesc& D = B.d[di];
  int local = bx - D.blk0;
  int bn = local % D.nbx, bk = local / D.nbx;
  const int n0 = bn * 32, k0 = bk * 32;
  const int tx = threadIdx.x & 31, ty = threadIdx.x >> 5;  // 32 x 8
  #pragma unroll
  for (int r0 = 0; r0 < 32; r0 += 8) {
    int k = k0 + r0 + ty, n = n0 + tx;
    tile[r0 + ty][tx] = (k < D.K && n < D.N) ? D.W[(size_t)k * D.N + n] : 0.f;
  }
  __syncthreads();
  #pragma unroll
  for (int r0 = 0; r0 < 32; r0 += 8) {
    int n = n0 + r0 + ty, kk = k0 + tx;
    float v = tile[tx][r0 + ty];
    ushort h = f2bf(v);
    D.Wh[(size_t)n * D.Kpad + kk] = h;
    D.Wl[(size_t)n * D.Kpad + kk] = f2bf(v - bf2f(h));
  }
}

// ---------------- w2rowsum: W2Th row 800 <- sum_n W2[k][n] (bf16 hi) ----------------
__global__ __launch_bounds__(256) void w2rowsum(const float* __restrict__ W2,
                                                ushort* __restrict__ W2Th) {
  int k = blockIdx.x * 4 + (threadIdx.x >> 6);
  int lane = threadIdx.x & 63;
  const float* row = W2 + (size_t)k * EMB;
  float s = 0.f;
  for (int n = lane; n < EMB; n += 64) s += row[n];
  #pragma unroll
  for (int m = 1; m < 64; m <<= 1) s += __shfl_xor(s, m);
  if (lane == 0 && k < P_H1) W2Th[800 * 1024 + k] = f2bf(s);
}

// ---------------- row LayerNorm (in-place), optional relu ----------------
template <bool RELU>
__global__ __launch_bounds__(256) void ln_rows(float* __restrict__ X,
                                               const float* __restrict__ g,
                                               const float* __restrict__ b, int N) {
  int row = blockIdx.x, tid = threadIdx.x;
  float* x = X + row * N;
  float s1 = 0.f, s2 = 0.f;
  for (int i = tid; i < N; i += 256) { float v = x[i]; s1 += v; s2 += v * v; }
  #pragma unroll
  for (int m = 1; m < 64; m <<= 1) { s1 += __shfl_xor(s1, m); s2 += __shfl_xor(s2, m); }
  __shared__ float r1[4], r2[4];
  int wv = tid >> 6;
  if ((tid & 63) == 0) { r1[wv] = s1; r2[wv] = s2; }
  __syncthreads();
  s1 = r1[0] + r1[1] + r1[2] + r1[3];
  s2 = r2[0] + r2[1] + r2[2] + r2[3];
  float inv = 1.f / (float)N;
  float mu = s1 * inv;
  float rstd = rsqrtf(s2 * inv - mu * mu + 1e-5f);
  for (int i = tid; i < N; i += 256) {
    float v = (x[i] - mu) * rstd * g[i] + b[i];
    if (RELU) v = fmaxf(v, 0.f);
    x[i] = v;
  }
}

// ---------------- prep_imgg: imgg = t3 * gn -> hi/lo bf16 [256][800] ----------------
__global__ __launch_bounds__(256) void prep_imgg(const float* __restrict__ t3,
                                                 const float* __restrict__ gn,
                                                 ushort* __restrict__ gh,
                                                 ushort* __restrict__ gl) {
  int r = blockIdx.x;
  for (int n = threadIdx.x; n < EMB; n += 256) {
    float v = t3[r * EMB + n] * gn[n];
    ushort h = f2bf(v);
    gh[r * EMB + n] = h;
    gl[r * EMB + n] = f2bf(v - bf2f(h));
  }
}

// ---------------- prep_pairB: per-b scalars S,T,ib2 ; aux[0]=sumb2/800 ----------------
__global__ __launch_bounds__(256) void prep_pairB(const float* __restrict__ t3,
                                                  const float* __restrict__ gn,
                                                  const float* __restrict__ bn,
                                                  const float* __restrict__ b2,
                                                  float* __restrict__ Sv, float* __restrict__ Tv,
                                                  float* __restrict__ IBv, float* __restrict__ aux) {
  int b = blockIdx.x, tid = threadIdx.x;
  __shared__ float r1[4], r2[4], r3[4];
  float s1 = 0.f, s2 = 0.f, s3 = 0.f;
  if (b == BB) {
    for (int n = tid; n < EMB; n += 256) s1 += b2[n];
    #pragma unroll
    for (int m = 1; m < 64; m <<= 1) s1 += __shfl_xor(s1, m);
    if ((tid & 63) == 0) r1[tid >> 6] = s1;
    __syncthreads();
    if (tid == 0) aux[0] = (r1[0] + r1[1] + r1[2] + r1[3]) * (1.f / EMB);
    return;
  }
  const float* row = t3 + b * EMB;
  for (int n = tid; n < EMB; n += 256) {
    float iv = row[n];
    float ig = iv * gn[n];
    s1 += ig; s2 += iv * bn[n]; s3 += ig * b2[n];
  }
  #pragma unroll
  for (int m = 1; m < 64; m <<= 1) {
    s1 += __shfl_xor(s1, m); s2 += __shfl_xor(s2, m); s3 += __shfl_xor(s3, m);
  }
  int wv = tid >> 6;
  if ((tid & 63) == 0) { r1[wv] = s1; r2[wv] = s2; r3[wv] = s3; }
  __syncthreads();
  if (tid == 0) {
    Sv[b] = r1[0] + r1[1] + r1[2] + r1[3];
    Tv[b] = r2[0] + r2[1] + r2[2] + r2[3];
    IBv[b] = r3[0] + r3[1] + r3[2] + r3[3];
  }
}

// ---------------- ugen: U[p][k]=relu(LN1(B1[a]+O1[o])) -> bf16 hi/lo, lane-contiguous ------
__global__ __launch_bounds__(256) void ugen(const float* __restrict__ B1v,
                                            const float* __restrict__ O1v,
                                            const float* __restrict__ g1,
                                            const float* __restrict__ be1,
                                            ushort* __restrict__ Uh,
                                            ushort* __restrict__ Ul, int p0) {
  int r = blockIdx.x * 4 + (threadIdx.x >> 6);
  int lane = threadIdx.x & 63;
  int p = p0 + r;
  if (p > NPAIR - 1) p = NPAIR - 1;
  int a = p / NOBJS, o = p - a * NOBJS;
  const float* br = B1v + a * P_H1;
  const float* ow = O1v + o * P_H1;
  const int kb = lane * 16;
  float x[16];
  float s1 = 0.f, s2 = 0.f;
  #pragma unroll
  for (int i = 0; i < 16; ++i) {
    int k = kb + i;
    float v = (k < P_H1) ? br[k] + ow[k] : 0.f;
    x[i] = v; s1 += v; s2 += v * v;
  }
  #pragma unroll
  for (int m = 1; m < 64; m <<= 1) { s1 += __shfl_xor(s1, m); s2 += __shfl_xor(s2, m); }
  float mu = s1 * (1.f / P_H1);
  float rstd = rsqrtf(s2 * (1.f / P_H1) - mu * mu + 1e-5f);
  ushort hv[16], lv[16];
  #pragma unroll
  for (int i = 0; i < 16; ++i) {
    int k = kb + i;
    float un = (k < P_H1) ? fmaxf((x[i] - mu) * rstd * g1[k] + be1[k], 0.f) : 0.f;
    ushort h = f2bf(un);
    hv[i] = h;
    lv[i] = f2bf(un - bf2f(h));
  }
  size_t base = (size_t)r * 1024 + kb;
  *(short8v*)&Uh[base] = *(short8v*)&hv[0];
  *(short8v*)&Uh[base + 8] = *(short8v*)&hv[8];
  *(short8v*)&Ul[base] = *(short8v*)&lv[0];
  *(short8v*)&Ul[base + 8] = *(short8v*)&lv[8];
}

// ---------------- ustat: per-pair LN2 stats via 1-product bf16 MFMA ----------------
// Vraw[p][n] = sum_k u[p][k] W2T[n][k] + b2[n]; mu via W2Th row 800 = w2rowsum.
__global__ __launch_bounds__(256, 3) void ustat(const ushort* __restrict__ Uh,
                                                const ushort* __restrict__ W2Th,
                                                const float* __restrict__ b2,
                                                const float* __restrict__ aux,
                                                float* __restrict__ muv,
                                                float* __restrict__ rstdv) {
  __shared__ ushort smem[8192];    // 2 x [128][32]
  __shared__ float red[2][128];
  const int tid = threadIdx.x, lane = tid & 63, wid = tid >> 6;
  const int wm = wid >> 1, wn = wid & 1;
  const int m0 = blockIdx.x * 128;
  const int lr = lane & 15, lk = lane >> 4;
  const int srow = lane >> 2;
  const int scol = (lane & 3) * 8;
  const float aux0 = aux[0];

  float ss[4][4] = {};
  float md[4][4] = {};

  for (int nt = 0; nt < 7; ++nt) {
    f32x4 acc[4][4];
    #pragma unroll
    for (int i = 0; i < 4; ++i)
      #pragma unroll
      for (int j = 0; j < 4; ++j) acc[i][j] = (f32x4){0.f, 0.f, 0.f, 0.f};

    for (int k0 = 0; k0 < 1024; k0 += 32) {
      __syncthreads();
      #pragma unroll
      for (int j = 0; j < 4; ++j) {
        int t = wid + 4 * j;  // 0..15
        int buf = t >> 3, i = t & 7;
        const ushort* src = buf == 0
            ? Uh + (size_t)(m0 + i * 16 + srow) * 1024 + k0 + scol
            : W2Th + (size_t)(nt * 128 + i * 16 + srow) * 1024 + k0 + scol;
        async_copy16(smem + buf * 4096 + i * 512, src);
      }
      __syncthreads();
      short8v ah[4], bh[4];
      #pragma unroll
      for (int f = 0; f < 4; ++f) {
        ah[f] = *(const short8v*)&smem[(wm * 64 + f * 16 + lr) * 32 + lk * 8];
        bh[f] = *(const short8v*)&smem[4096 + (wn * 64 + f * 16 + lr) * 32 + lk * 8];
      }
      #pragma unroll
      for (int mi = 0; mi < 4; ++mi)
        #pragma unroll
        for (int ni = 0; ni < 4; ++ni)
          acc[mi][ni] = __builtin_amdgcn_mfma_f32_16x16x32_bf16(ah[mi], bh[ni], acc[mi][ni], 0, 0, 0);
    }
    // accumulate row sums of squares (cols n<800, with +b2), capture mu-dot at n==800
    #pragma unroll
    for (int ni = 0; ni < 4; ++ni) {
      int n = nt * 128 + wn * 64 + ni * 16 + lr;
      if (n < EMB) {
        float bb = b2[n];
        #pragma unroll
        for (int mi = 0; mi < 4; ++mi)
          #pragma unroll
          for (int r = 0; r < 4; ++r) {
            float v = acc[mi][ni][r] + bb;
            ss[mi][r] += v * v;
          }
      } else if (n == EMB) {
        #pragma unroll
        for (int mi = 0; mi < 4; ++mi)
          #pragma unroll
          for (int r = 0; r < 4; ++r) md[mi][r] = acc[mi][ni][r];
      }
    }
  }
  // reduce ss across the 16 lr lanes
  #pragma unroll
  for (int mi = 0; mi < 4; ++mi)
    #pragma unroll
    for (int r = 0; r < 4; ++r) {
      float s = ss[mi][r];
      s += __shfl_xor(s, 1); s += __shfl_xor(s, 2);
      s += __shfl_xor(s, 4); s += __shfl_xor(s, 8);
      ss[mi][r] = s;
    }
  if (lr == 0) {
    #pragma unroll
    for (int mi = 0; mi < 4; ++mi)
      #pragma unroll
      for (int r = 0; r < 4; ++r)
        red[wn][wm * 64 + mi * 16 + lk * 4 + r] = ss[mi][r];
  }
  __syncthreads();
  if (wn == 0 && lr == 0) {
    #pragma unroll
    for (int mi = 0; mi < 4; ++mi)
      #pragma unroll
      for (int r = 0; r < 4; ++r) {
        int row = wm * 64 + mi * 16 + lk * 4 + r;
        float tot = red[0][row] + red[1][row];
        float m_ = md[mi][r] * (1.f / EMB) + aux0;
        muv[m0 + row] = m_;
        rstdv[m0 + row] = rsqrtf(tot * (1.f / EMB) - m_ * m_ + 1e-5f);
      }
  }
}

// ---------------- universal bf16 hi/lo 3-product MFMA GEMM ----------------
template <bool HAS2, bool HASBIAS, bool RELU, bool PAIREPI>
__global__ __launch_bounds__(256, 3) void gemm_mf(
    const ushort* __restrict__ Ah, const ushort* __restrict__ Al, int lda,
    const ushort* __restrict__ Bh, const ushort* __restrict__ Bl, int ldb,
    const ushort* __restrict__ A2h, const ushort* __restrict__ A2l, int lda2,
    const ushort* __restrict__ B2h, const ushort* __restrict__ B2l, int ldb2,
    const float* __restrict__ bias, float* __restrict__ C, size_t ldc,
    int K, int Mvalid, int nvalid, int ncol0,
    const float* __restrict__ rstdv, const float* __restrict__ muv,
    const float* __restrict__ Sv, const float* __restrict__ Tv,
    const float* __restrict__ IBv) {
  __shared__ ushort smem[16384];  // 4 x [128][32]
  const int tid = threadIdx.x, lane = tid & 63, wid = tid >> 6;
  const int wm = wid >> 1, wn = wid & 1;
  const int n0b = blockIdx.x * 128, m0 = blockIdx.y * 128;
  const int lr = lane & 15, lk = lane >> 4;

  f32x4 acc[4][4];
  #pragma unroll
  for (int i = 0; i < 4; ++i)
    #pragma unroll
    for (int j = 0; j < 4; ++j) acc[i][j] = (f32x4){0.f, 0.f, 0.f, 0.f};

  const int srow = lane >> 2;
  const int scol = (lane & 3) * 8;
  const int npass = HAS2 ? 2 : 1;

  for (int pass = 0; pass < npass; ++pass) {
    const ushort* pAh = (HAS2 && pass) ? A2h : Ah;
    const ushort* pAl = (HAS2 && pass) ? A2l : Al;
    const ushort* pBh = (HAS2 && pass) ? B2h : Bh;
    const ushort* pBl = (HAS2 && pass) ? B2l : Bl;
    const int plda = (HAS2 && pass) ? lda2 : lda;
    const int pldb = (HAS2 && pass) ? ldb2 : ldb;

    for (int k0 = 0; k0 < K; k0 += 32) {
      __syncthreads();
      #pragma unroll
      for (int j = 0; j < 8; ++j) {
        int t = wid + 4 * j;
        int buf = t >> 3, i = t & 7;
        const ushort* g;
        int ld_, r0;
        if (buf == 0)      { g = pAh; ld_ = plda; r0 = m0; }
        else if (buf == 1) { g = pAl; ld_ = plda; r0 = m0; }
        else if (buf == 2) { g = pBh; ld_ = pldb; r0 = n0b; }
        else               { g = pBl; ld_ = pldb; r0 = n0b; }
        const ushort* src = g + (size_t)(r0 + i * 16 + srow) * ld_ + k0 + scol;
        async_copy16(smem + buf * 4096 + i * 512, src);
      }
      __syncthreads();

      short8v ah[4], al[4], bh[4], bl[4];
      #pragma unroll
      for (int f = 0; f < 4; ++f) {
        ah[f] = *(const short8v*)&smem[0     + (wm * 64 + f * 16 + lr) * 32 + lk * 8];
        al[f] = *(const short8v*)&smem[4096  + (wm * 64 + f * 16 + lr) * 32 + lk * 8];
        bh[f] = *(const short8v*)&smem[8192  + (wn * 64 + f * 16 + lr) * 32 + lk * 8];
        bl[f] = *(const short8v*)&smem[12288 + (wn * 64 + f * 16 + lr) * 32 + lk * 8];
      }
      #pragma unroll
      for (int mi = 0; mi < 4; ++mi)
        #pragma unroll
        for (int ni = 0; ni < 4; ++ni) {
          acc[mi][ni] = __builtin_amdgcn_mfma_f32_16x16x32_bf16(ah[mi], bh[ni], acc[mi][ni], 0, 0, 0);
          acc[mi][ni] = __builtin_amdgcn_mfma_f32_16x16x32_bf16(al[mi], bh[ni], acc[mi][ni], 0, 0, 0);
          acc[mi][ni] = __builtin_amdgcn_mfma_f32_16x16x32_bf16(ah[mi], bl[ni], acc[mi][ni], 0, 0, 0);
        }
    }
  }

  // epilogue: C/D layout col=lane&15, row=(lane>>4)*4+reg  [m89-verified]
  #pragma unroll
  for (int mi = 0; mi < 4; ++mi)
    #pragma unroll
    for (int ni = 0; ni < 4; ++ni) {
      int n = n0b + wn * 64 + ni * 16 + lr;
      if (n >= nvalid) continue;
      float rs = 0.f, mn = 0.f;
      if (PAIREPI) { rs = rstdv[n]; mn = muv[n]; }
      float bb = (HASBIAS && !PAIREPI) ? bias[n] : 0.f;
      #pragma unroll
      for (int r = 0; r < 4; ++r) {
        int m = m0 + wm * 64 + mi * 16 + lk * 4 + r;
        if (m >= Mvalid) continue;
        float v = acc[mi][ni][r];
        if (PAIREPI) {
          v = rs * (v + IBv[m] - mn * Sv[m]) + Tv[m];
        } else {
          v += bb;
          if (RELU) v = fmaxf(v, 0.f);
        }
        C[(size_t)m * ldc + ncol0 + n] = v;
      }
    }
}

// ---------------- launch ----------------
extern "C" void kernel_launch(void* const* d_in, const int* in_sizes, int n_in,
                              void* d_out, int out_size, void* d_ws, size_t ws_size,
                              hipStream_t stream) {
  const float* img = (const float*)d_in[0];
  const float* node_feats = (const float*)d_in[1];
  const int* ei = (const int*)d_in[2];
  const float* s1_Wl = (const float*)d_in[3];
  const float* s1_bl = (const float*)d_in[4];
  const float* s1_Wr = (const float*)d_in[5];
  const float* s2_Wl = (const float*)d_in[6];
  const float* s2_bl = (const float*)d_in[7];
  const float* s2_Wr = (const float*)d_in[8];
  const float* i_W1 = (const float*)d_in[9];
  const float* i_b1 = (const float*)d_in[10];
  const float* i_g1 = (const float*)d_in[11];
  const float* i_be1 = (const float*)d_in[12];
  const float* i_W2 = (const float*)d_in[13];
  const float* i_b2 = (const float*)d_in[14];
  const float* i_g2 = (const float*)d_in[15];
  const float* i_be2 = (const float*)d_in[16];
  const float* i_W3 = (const float*)d_in[17];
  const float* i_b3 = (const float*)d_in[18];
  const float* i_gn = (const float*)d_in[19];
  const float* i_bn = (const float*)d_in[20];
  const float* p_W1 = (const float*)d_in[21];
  const float* p_b1 = (const float*)d_in[22];
  const float* p_g1 = (const float*)d_in[23];
  const float* p_be1 = (const float*)d_in[24];
  const float* p_W2 = (const float*)d_in[25];
  const float* p_b2 = (const float*)d_in[26];
  const float* p_gn = (const float*)d_in[27];
  const float* p_bn = (const float*)d_in[28];

  const int E = in_sizes[2] / 2;

  // -------- workspace layout --------
  char* base = (char*)d_ws;
  size_t off = 0;
  auto alloc = [&](size_t bytes) -> void* {
    void* p = base + off;
    off = (off + bytes + 255) & ~(size_t)255;
    return p;
  };
  float* mean1 = (float*)alloc(700 * 512 * 4);
  float* h     = (float*)alloc(700 * 2048 * 4);
  float* mean2 = (float*)alloc(700 * 2048 * 4);
  float* t1    = (float*)alloc(256 * 800 * 4);
  float* t2    = (float*)alloc(256 * 1000 * 4);
  float* t3    = (float*)alloc(256 * 800 * 4);
  float* B1    = (float*)alloc(200 * 1000 * 4);
  float* O1    = (float*)alloc(500 * 1000 * 4);
  float* G     = (float*)alloc(256 * 1024 * 4);
  ushort* nfh = (ushort*)alloc(768 * 512 * 2);
  ushort* nfl = (ushort*)alloc(768 * 512 * 2);
  ushort* m1h = (ushort*)alloc(768 * 512 * 2);
  ushort* m1l = (ushort*)alloc(768 * 512 * 2);
  ushort* hh  = (ushort*)alloc(768 * 2048 * 2);
  ushort* hl  = (ushort*)alloc(768 * 2048 * 2);
  ushort* m2h = (ushort*)alloc(768 * 2048 * 2);
  ushort* m2l = (ushort*)alloc(768 * 2048 * 2);
  ushort* ndh = (ushort*)alloc(768 * 512 * 2);
  ushort* ndl = (ushort*)alloc(768 * 512 * 2);
  ushort* xih = (ushort*)alloc(256 * 512 * 2);
  ushort* xil = (ushort*)alloc(256 * 512 * 2);
  ushort* t1h = (ushort*)alloc(256 * 800 * 2);
  ushort* t1l = (ushort*)alloc(256 * 800 * 2);
  ushort* t2h = (ushort*)alloc(256 * 1024 * 2);
  ushort* t2l = (ushort*)alloc(256 * 1024 * 2);
  ushort* iggh = (ushort*)alloc(256 * 800 * 2);
  ushort* iggl = (ushort*)alloc(256 * 800 * 2);
  ushort* Gh   = (ushort*)alloc(256 * 1024 * 2);
  ushort* Gl   = (ushort*)alloc(256 * 1024 * 2);
  ushort* w1lh = (ushort*)alloc((size_t)2048 * 512 * 2);
  ushort* w1ll = (ushort*)alloc((size_t)2048 * 512 * 2);
  ushort* w1rh = (ushort*)alloc((size_t)2048 * 512 * 2);
  ushort* w1rl = (ushort*)alloc((size_t)2048 * 512 * 2);
  ushort* w2lh = (ushort*)alloc((size_t)512 * 2048 * 2);
  ushort* w2ll = (ushort*)alloc((size_t)512 * 2048 * 2);
  ushort* w2rh = (ushort*)alloc((size_t)512 * 2048 * 2);
  ushort* w2rl = (ushort*)alloc((size_t)512 * 2048 * 2);
  ushort* iw1h = (ushort*)alloc((size_t)896 * 512 * 2);
  ushort* iw1l = (ushort*)alloc((size_t)896 * 512 * 2);
  ushort* iw2h = (ushort*)alloc((size_t)1024 * 800 * 2);
  ushort* iw2l = (ushort*)alloc((size_t)1024 * 800 * 2);
  ushort* iw3h = (ushort*)alloc((size_t)896 * 1024 * 2);
  ushort* iw3l = (ushort*)alloc((size_t)896 * 1024 * 2);
  ushort* pw1ah = (ushort*)alloc((size_t)1024 * 512 * 2);
  ushort* pw1al = (ushort*)alloc((size_t)1024 * 512 * 2);
  ushort* pw1bh = (ushort*)alloc((size_t)1024 * 512 * 2);
  ushort* pw1bl = (ushort*)alloc((size_t)1024 * 512 * 2);
  ushort* W2Th = (ushort*)alloc((size_t)896 * 1024 * 2);
  ushort* W2Tl = (ushort*)alloc((size_t)896 * 1024 * 2);
  ushort* Wkh  = (ushort*)alloc((size_t)1024 * 800 * 2);
  ushort* Wkl  = (ushort*)alloc((size_t)1024 * 800 * 2);
  float* Sv  = (float*)alloc(256 * 4);
  float* Tv  = (float*)alloc(256 * 4);
  float* IBv = (float*)alloc(256 * 4);
  float* aux = (float*)alloc(256);
  int* cnt       = (int*)alloc(704 * 4);
  int* row_start = (int*)alloc(704 * 4);
  int* pos       = (int*)alloc(704 * 4);
  int* srcs      = (int*)alloc(50176 * 4);

  // chunk buffers: per pair row: Uh 2048 + Ul 2048 + mu 4 + rstd 4 = 4104 B
  size_t avail = (ws_size > off + (4u << 20)) ? ws_size - off - (4u << 20) : 0;
  long maxRows = (long)(avail / 4104) - 256;
  int CA = (int)(maxRows / 500);
  if (CA < 1) CA = 1;
  if (CA > NATTRS) CA = NATTRS;
  int nch = (NATTRS + CA - 1) / CA;
  int rowsPadAlloc = ((CA * 500 + 127) / 128) * 128;
  ushort* Uh    = (ushort*)alloc((size_t)rowsPadAlloc * 1024 * 2);
  ushort* Ul    = (ushort*)alloc((size_t)rowsPadAlloc * 1024 * 2);
  float*  muv   = (float*)alloc((size_t)rowsPadAlloc * 4);
  float*  rstdv = (float*)alloc((size_t)rowsPadAlloc * 4);

  float* pairp = (float*)d_out;
  float* nodes = (float*)d_out + (size_t)BB * NPAIR;

  const ushort* NU = nullptr;
  const float* NUF = nullptr;

  // -------- CSR build --------
  hipMemsetAsync(cnt, 0, NNODE * sizeof(int), stream);
  k_count<<<(E + 255) / 256, 256, 0, stream>>>(ei, cnt, E);
  k_scan<<<1, 1024, 0, stream>>>(cnt, row_start, pos);
  k_fill<<<(E + 255) / 256, 256, 0, stream>>>(ei, pos, srcs, E);

  // -------- batched weight prep (one launch for all 10 transposes) --------
  {
    WBatch B;
    int blk = 0;
    auto set = [&](int i, const float* W, ushort* Wh, ushort* Wl, int K, int N, int Kpad, int Npad) {
      B.d[i] = {W, Wh, Wl, K, N, Kpad, Npad / 32, blk};
      blk += (Npad / 32) * (Kpad / 32);
    };
    set(0, s1_Wl, w1lh, w1ll, 512, 2048, 512, 2048);
    set(1, s1_Wr, w1rh, w1rl, 512, 2048, 512, 2048);
    set(2, s2_Wl, w2lh, w2ll, 2048, 512, 2048, 512);
    set(3, s2_Wr, w2rh, w2rl, 2048, 512, 2048, 512);
    set(4, i_W1, iw1h, iw1l, 512, 800, 512, 896);
    set(5, i_W2, iw2h, iw2l, 800, 1000, 800, 1024);
    set(6, i_W3, iw3h, iw3l, 1000, 800, 1024, 896);
    set(7, p_W1, pw1ah, pw1al, 512, 1000, 512, 1024);
    set(8, p_W1 + 512 * 1000, pw1bh, pw1bl, 512, 1000, 512, 1024);
    set(9, p_W2, W2Th, W2Tl, 1000, 800, 1024, 896);
    prep_wT_batch<<<blk, 256, 0, stream>>>(B);
  }
  w2rowsum<<<250, 256, 0, stream>>>(p_W2, W2Th);
  // W2 as [1000][800] row-major -> zero-padded hi/lo [1024][800] (B operand of G-GEMM)
  split_f32<<<512, 256, 0, stream>>>(p_W2, Wkh, Wkl, 1000, 800, 800, 1024L * 800);

  // -------- SAGE layer 1 --------
  agg_mean<<<dim3(NNODE, IN_F / 256), 256, 0, stream>>>(node_feats, srcs, row_start, mean1, IN_F);
  split_f32<<<512, 256, 0, stream>>>(node_feats, nfh, nfl, 700, 512, 512, 768L * 512);
  split_f32<<<512, 256, 0, stream>>>(mean1, m1h, m1l, 700, 512, 512, 768L * 512);
  gemm_mf<true, true, true, false><<<dim3(16, 6), 256, 0, stream>>>(
      m1h, m1l, 512, w1lh, w1ll, 512, nfh, nfl, 512, w1rh, w1rl, 512,
      s1_bl, h, 2048, 512, 700, 2048, 0, NUF, NUF, NUF, NUF, NUF);

  // -------- SAGE layer 2 --------
  agg_mean<<<dim3(NNODE, HID / 256), 256, 0, stream>>>(h, srcs, row_start, mean2, HID);
  split_f32<<<1024, 256, 0, stream>>>(h, hh, hl, 700, 2048, 2048, 768L * 2048);
  split_f32<<<1024, 256, 0, stream>>>(mean2, m2h, m2l, 700, 2048, 2048, 768L * 2048);
  gemm_mf<true, true, false, false><<<dim3(4, 6), 256, 0, stream>>>(
      m2h, m2l, 2048, w2lh, w2ll, 2048, hh, hl, 2048, w2rh, w2rl, 2048,
      s2_bl, nodes, 512, 2048, 700, 512, 0, NUF, NUF, NUF, NUF, NUF);

  // -------- image branch --------
  split_f32<<<256, 256, 0, stream>>>(img, xih, xil, 256, 512, 512, 256L * 512);
  gemm_mf<false, true, false, false><<<dim3(7, 2), 256, 0, stream>>>(
      xih, xil, 512, iw1h, iw1l, 512, NU, NU, 0, NU, NU, 0,
      i_b1, t1, 800, 512, 256, 800, 0, NUF, NUF, NUF, NUF, NUF);
  ln_rows<true><<<BB, 256, 0, stream>>>(t1, i_g1, i_be1, 800);
  split_f32<<<256, 256, 0, stream>>>(t1, t1h, t1l, 256, 800, 800, 256L * 800);
  gemm_mf<false, true, false, false><<<dim3(8, 2), 256, 0, stream>>>(
      t1h, t1l, 800, iw2h, iw2l, 800, NU, NU, 0, NU, NU, 0,
      i_b2, t2, 1000, 800, 256, 1000, 0, NUF, NUF, NUF, NUF, NUF);
  ln_rows<true><<<BB, 256, 0, stream>>>(t2, i_g2, i_be2, 1000);
  split_f32<<<256, 256, 0, stream>>>(t2, t2h, t2l, 256, 1000, 1024, 256L * 1024);
  gemm_mf<false, true, false, false><<<dim3(7, 2), 256, 0, stream>>>(
      t2h, t2l, 1024, iw3h, iw3l, 1024, NU, NU, 0, NU, NU, 0,
      i_b3, t3, 800, 1024, 256, 800, 0, NUF, NUF, NUF, NUF, NUF);
  ln_rows<false><<<BB, 256, 0, stream>>>(t3, i_gn, i_bn, EMB);

  // -------- pair-branch constants: S,T,ib2,aux ; G = (img.gn) @ W2^T --------
  prep_pairB<<<BB + 1, 256, 0, stream>>>(t3, p_gn, p_bn, p_b2, Sv, Tv, IBv, aux);
  prep_imgg<<<BB, 256, 0, stream>>>(t3, p_gn, iggh, iggl);
  gemm_mf<false, false, false, false><<<dim3(8, 2), 256, 0, stream>>>(
      iggh, iggl, 800, Wkh, Wkl, 800, NU, NU, 0, NU, NU, 0,
      nullptr, G, 1024, 800, 256, 1024, 0, NUF, NUF, NUF, NUF, NUF);
  split_f32<<<256, 256, 0, stream>>>(G, Gh, Gl, 256, 1024, 1024, 256L * 1024);

  // -------- B1 / O1 --------
  split_f32<<<512, 256, 0, stream>>>(nodes, ndh, ndl, 700, 512, 512, 768L * 512);
  gemm_mf<false, true, false, false><<<dim3(8, 2), 256, 0, stream>>>(
      ndh, ndl, 512, pw1ah, pw1al, 512, NU, NU, 0, NU, NU, 0,
      p_b1, B1, 1000, 512, 200, 1000, 0, NUF, NUF, NUF, NUF, NUF);
  gemm_mf<false, false, false, false><<<dim3(8, 4), 256, 0, stream>>>(
      ndh + 200 * 512, ndl + 200 * 512, 512, pw1bh, pw1bl, 512, NU, NU, 0, NU, NU, 0,
      nullptr, O1, 1000, 512, 500, 1000, 0, NUF, NUF, NUF, NUF, NUF);

  // -------- chunked pair branch: ugen -> ustat (LN2 stats) -> out-GEMM --------
  for (int c = 0; c < nch; ++c) {
    int a0 = c * CA;
    int ca = (NATTRS - a0 < CA) ? (NATTRS - a0) : CA;
    int rows = ca * 500;
    int rowsPad = ((rows + 127) / 128) * 128;
    int p0 = a0 * 500;

    ugen<<<rowsPad / 4, 256, 0, stream>>>(B1, O1, p_g1, p_be1, Uh, Ul, p0);
    ustat<<<rowsPad / 128, 256, 0, stream>>>(Uh, W2Th, p_b2, aux, muv, rstdv);
    gemm_mf<false, false, false, true><<<dim3(rowsPad / 128, 2), 256, 0, stream>>>(
        Gh, Gl, 1024, Uh, Ul, 1024, NU, NU, 0, NU, NU, 0,
        nullptr, pairp, NPAIR, 1024, 256, rows, p0,
        rstdv, muv, Sv, Tv, IBv);
  }
}